// Round 5
// baseline (116.903 us; speedup 1.0000x reference)
//
#include <hip/hip_runtime.h>

#define IN_DIM  4096
#define OUT_DIM 4096
#define RANK    16
#define NBLK    16
#define KDIM    256   // NBLK*RANK

typedef __attribute__((ext_vector_type(8))) __bf16 bf16x8;
typedef __attribute__((ext_vector_type(4))) __bf16 bf16x4;
typedef __attribute__((ext_vector_type(4))) float  f32x4;

// ---------------------------------------------------------------------------
// Pack layouts (MFMA 16x16x32 fragment order), granularity = bf16x8 (16B):
//   PackA[mt(128)][ko(32)][c(16)] : 8 bf16 = T[mt*16+c][ko*8+j]   (A row=c)
//   PackB[nt(256)][ko(32)][c(16)] : 8 bf16 = Ahat[ko*8+j][nt*16+c](B col=c)
//   PackV[i(16)][ks(8)][qt(4)][c(16)] : 8 bf16 = Vt[i][ks*32+qt*8+j][c]
// k of apply GEMM: k = i*16 + r = ko*8 + j.
// All values split hi/lo bf16 (w = hi + lo to ~16-bit mantissa).
// ---------------------------------------------------------------------------

__device__ __forceinline__ void split_bf16(float v, __bf16& h, __bf16& l) {
    h = (__bf16)v;
    l = (__bf16)(v - (float)h);
}

// blocks 0..511: B-pack (Ahat = S*U).  blocks 512..543: Vt-pack.
__global__ __launch_bounds__(256) void build_packs(const float* __restrict__ S,
                                                   const float* __restrict__ U,
                                                   const float* __restrict__ Vt,
                                                   bf16x8* __restrict__ Bhi,
                                                   bf16x8* __restrict__ Blo,
                                                   bf16x8* __restrict__ Vhi,
                                                   bf16x8* __restrict__ Vlo) {
    const int blk = blockIdx.x;
    if (blk < 512) {
        int t  = blk * 256 + threadIdx.x;  // = (nt*32 + ko)*16 + c
        int c  = t & 15;
        int ko = (t >> 4) & 31;
        int nt = t >> 9;
        int o  = nt >> 4;
        int i  = ko >> 1;
        int q  = ((nt & 15) << 4) | c;
        int r0 = (ko & 1) << 3;
        const float* Sp = S + ((o * NBLK + i) * RANK + r0);
        const float* Up = U + (size_t)o * RANK * 256 + q;   // + r*256
        bf16x8 hi, lo;
#pragma unroll
        for (int j = 0; j < 8; ++j) {
            float w = Sp[j] * Up[(size_t)(r0 + j) * 256];
            __bf16 h, l;
            split_bf16(w, h, l);
            hi[j] = h; lo[j] = l;
        }
        Bhi[t] = hi;
        Blo[t] = lo;
    } else {
        int t  = (blk - 512) * 256 + threadIdx.x;  // = ((i*8+ks)*4+qt)*16 + c
        int c  = t & 15;
        int p0 = (t >> 4) << 3;                    // (ks*32 + qt*8) within block i
        int i  = t >> 9;
        int pbase = (p0 & 255);
        const float* vp = Vt + ((size_t)(i * 256 + pbase)) * RANK + c;
        bf16x8 hi, lo;
#pragma unroll
        for (int j = 0; j < 8; ++j) {
            float w = vp[(size_t)j * RANK];
            __bf16 h, l;
            split_bf16(w, h, l);
            hi[j] = h; lo[j] = l;
        }
        Vhi[t] = hi;
        Vlo[t] = lo;
    }
}

// Stage A via MFMA:  D[r][m] = sum_p Vt[i][p][r] * x[m][p]  (per (mt, i) job)
__global__ __launch_bounds__(256) void factor_mfma(const float* __restrict__ x,
                                                   const bf16x8* __restrict__ Vhi,
                                                   const bf16x8* __restrict__ Vlo,
                                                   bf16x4* __restrict__ Ahi4,
                                                   bf16x4* __restrict__ Alo4,
                                                   float* __restrict__ rowsum_p,
                                                   int M) {
    const int tid = threadIdx.x;
    const int l   = tid & 63;
    const int w   = tid >> 6;
    const int job = blockIdx.x * 4 + w;     // (mt, i)
    const int i   = job & 15;
    const int mt  = job >> 4;
    const int row = l & 15;                 // m within tile (B col)
    const int qt  = l >> 4;                 // k-quarter

    const float* xp = x + (size_t)(mt * 16 + row) * IN_DIM + i * 256 + qt * 8;

    f32x4 acc = {0.f, 0.f, 0.f, 0.f};
    float rs = 0.f;
#pragma unroll
    for (int ks = 0; ks < 8; ++ks) {
        float4 a = *reinterpret_cast<const float4*>(xp + ks * 32);
        float4 b = *reinterpret_cast<const float4*>(xp + ks * 32 + 4);
        rs += (a.x + a.y) + (a.z + a.w) + (b.x + b.y) + (b.z + b.w);
        float vv[8] = {a.x, a.y, a.z, a.w, b.x, b.y, b.z, b.w};
        bf16x8 xh, xl;
#pragma unroll
        for (int jj = 0; jj < 8; ++jj) {
            __bf16 h, lo_;
            split_bf16(vv[jj], h, lo_);
            xh[jj] = h; xl[jj] = lo_;
        }
        size_t vidx = (size_t)((i * 8 + ks) * 4 + qt) * 16 + row;
        bf16x8 vh = Vhi[vidx];
        bf16x8 vl = Vlo[vidx];
        acc = __builtin_amdgcn_mfma_f32_16x16x32_bf16(vh, xh, acc, 0, 0, 0);
        acc = __builtin_amdgcn_mfma_f32_16x16x32_bf16(vh, xl, acc, 0, 0, 0);
        acc = __builtin_amdgcn_mfma_f32_16x16x32_bf16(vl, xh, acc, 0, 0, 0);
    }

    rs += __shfl_xor(rs, 16, 64);
    rs += __shfl_xor(rs, 32, 64);
    if (l < 16)
        rowsum_p[(size_t)i * M + mt * 16 + l] = rs;

    bf16x4 hi, lo;
#pragma unroll
    for (int reg = 0; reg < 4; ++reg) {
        __bf16 h, lo_;
        split_bf16(acc[reg], h, lo_);
        hi[reg] = h; lo[reg] = lo_;
    }
    size_t o4 = ((size_t)(mt * 32 + i * 2 + (l >> 5)) * 16 + row) * 2 + ((l >> 4) & 1);
    Ahi4[o4] = hi;
    Alo4[o4] = lo;
}

// out = T @ Ahat (split bf16: AhBh + AhBl + AlBh) + (1+rowsum[m])*bias[n]
// LDS-staged m97-style pipeline. grid 1024 x 256 thr; tile 64m x 128n; K=256.
// Per K-step chunk (32 k = 4 ko): A slices 8x1KB (hi,lo x 4 mt), B 16x1KB
// (hi,lo x 8 nt); double-buffered -> 48KB LDS, 3 blocks/CU.
__global__ __launch_bounds__(256, 3) void apply_mfma(const bf16x8* __restrict__ Ahi,
                                                     const bf16x8* __restrict__ Alo,
                                                     const bf16x8* __restrict__ Bhi,
                                                     const bf16x8* __restrict__ Blo,
                                                     const float* __restrict__ rowsum_p,
                                                     const float* __restrict__ bias,
                                                     float* __restrict__ out, int M) {
    __shared__ bf16x8 smem[2][1536];   // [buf][A: slices 0..7 | B: slices 8..23], 64 frags/slice
    __shared__ float rstot_s[64];

    const int nb  = blockIdx.x;
    const int q   = gridDim.x >> 3;             // 128 (grid 1024, %8==0)
    const int lg  = (nb & 7) * q + (nb >> 3);   // XCD-contiguous logical id
    const int mr  = lg & 31;
    const int nc  = lg >> 5;                    // 4 consecutive nc per XCD
    const int m0  = mr * 64, n0 = nc * 128;
    const int mtb0 = m0 >> 4;                   // 4 mt-tiles
    const int ntb0 = n0 >> 4;                   // 8 nt-tiles

    const int tid = threadIdx.x;
    const int l   = tid & 63;
    const int w   = __builtin_amdgcn_readfirstlane(tid >> 6);
    const int wm  = w & 1, wn = w >> 1;         // 2x2 waves: 32m x 64n each
    const int kq  = l >> 4, c = l & 15;

    // stage one 24KB chunk (K-step s) into buffer buf; 6 slices per wave
#define STAGE(s_, buf_)                                                              \
    {                                                                                \
        _Pragma("unroll")                                                            \
        for (int j = 0; j < 6; ++j) {                                                \
            const int sl = w * 6 + j;                                                \
            const bf16x8* gbase;                                                     \
            if (sl < 8) {                                                            \
                gbase = ((sl >> 2) ? Alo : Ahi)                                      \
                      + ((size_t)(mtb0 + (sl & 3)) * 32 + 4 * (s_)) * 16;            \
            } else {                                                                 \
                const int b = sl - 8;                                                \
                gbase = ((b >> 3) ? Blo : Bhi)                                       \
                      + ((size_t)(ntb0 + (b & 7)) * 32 + 4 * (s_)) * 16;             \
            }                                                                        \
            __builtin_amdgcn_global_load_lds(                                        \
                (const __attribute__((address_space(1))) unsigned*)(gbase + l),      \
                (__attribute__((address_space(3))) unsigned*)&smem[buf_][sl * 64],   \
                16, 0, 0);                                                           \
        }                                                                            \
    }

    f32x4 acc[2][4];
#pragma unroll
    for (int f = 0; f < 2; ++f)
#pragma unroll
        for (int nf = 0; nf < 4; ++nf) acc[f][nf] = f32x4{0.f, 0.f, 0.f, 0.f};

    STAGE(0, 0);
    if (tid < 64) {
        float ssum = 1.0f;
#pragma unroll
        for (int i = 0; i < NBLK; ++i) ssum += rowsum_p[(size_t)i * M + m0 + tid];
        rstot_s[tid] = ssum;
    }
    __syncthreads();

    for (int s = 0; s < 8; ++s) {
        if (s < 7) STAGE(s + 1, (s + 1) & 1);
        const bf16x8* sb = smem[s & 1];
        bf16x8 ah[2], al[2];
#pragma unroll
        for (int f = 0; f < 2; ++f) {
            ah[f] = sb[(wm * 2 + f) * 64 + l];
            al[f] = sb[(4 + wm * 2 + f) * 64 + l];
        }
#pragma unroll
        for (int nf = 0; nf < 4; ++nf) {
            bf16x8 bh = sb[512 + (wn * 4 + nf) * 64 + l];
            bf16x8 bl = sb[1024 + (wn * 4 + nf) * 64 + l];
#pragma unroll
            for (int f = 0; f < 2; ++f) {
                acc[f][nf] = __builtin_amdgcn_mfma_f32_16x16x32_bf16(ah[f], bh, acc[f][nf], 0, 0, 0);
                acc[f][nf] = __builtin_amdgcn_mfma_f32_16x16x32_bf16(ah[f], bl, acc[f][nf], 0, 0, 0);
                acc[f][nf] = __builtin_amdgcn_mfma_f32_16x16x32_bf16(al[f], bh, acc[f][nf], 0, 0, 0);
            }
        }
        __syncthreads();
    }
#undef STAGE

    // epilogue: out[m][n] = acc + rstot[m]*bias[n]   (C/D: row=kq*4+reg, col=c)
#pragma unroll
    for (int f = 0; f < 2; ++f) {
        const int rloc = wm * 32 + f * 16 + kq * 4;
        const int rowb = m0 + rloc;
        float rsv[4];
#pragma unroll
        for (int reg = 0; reg < 4; ++reg) rsv[reg] = rstot_s[rloc + reg];
#pragma unroll
        for (int nf = 0; nf < 4; ++nf) {
            const int n = n0 + wn * 64 + nf * 16 + c;
            const float bv = bias[n];
#pragma unroll
            for (int reg = 0; reg < 4; ++reg)
                out[(size_t)(rowb + reg) * OUT_DIM + n] = acc[f][nf][reg] + rsv[reg] * bv;
        }
    }
}

extern "C" void kernel_launch(void* const* d_in, const int* in_sizes, int n_in,
                              void* d_out, int out_size, void* d_ws, size_t ws_size,
                              hipStream_t stream) {
    const float* x    = (const float*)d_in[0];
    const float* S    = (const float*)d_in[1];
    const float* U    = (const float*)d_in[2];
    const float* Vt   = (const float*)d_in[3];
    const float* bias = (const float*)d_in[4];
    float* out = (float*)d_out;
    const int M = in_sizes[0] / IN_DIM;   // 2048

    char* ws = (char*)d_ws;
    bf16x8* Bhi     = (bf16x8*)ws;                                    // 2 MB
    bf16x8* Blo     = (bf16x8*)(ws + (2u << 20));                     // 2 MB
    bf16x8* Ahi     = (bf16x8*)(ws + (4u << 20));                     // 1 MB
    bf16x8* Alo     = (bf16x8*)(ws + (5u << 20));                     // 1 MB
    bf16x8* Vhi     = (bf16x8*)(ws + (6u << 20));                     // 128 KB
    bf16x8* Vlo     = (bf16x8*)(ws + (6u << 20) + (128u << 10));      // 128 KB
    float* rowsum_p = (float*)(ws + (6u << 20) + (256u << 10));       // 128 KB

    build_packs<<<544, 256, 0, stream>>>(S, U, Vt, Bhi, Blo, Vhi, Vlo);
    factor_mfma<<<M / 4, 256, 0, stream>>>(x, Vhi, Vlo,
                                           (bf16x4*)Ahi, (bf16x4*)Alo, rowsum_p, M);
    apply_mfma<<<(M / 64) * (OUT_DIM / 128), 256, 0, stream>>>(
        Ahi, Alo, Bhi, Blo, rowsum_p, bias, out, M);
}

// Round 6
// 108.896 us; speedup vs baseline: 1.0735x; 1.0735x over previous
//
#include <hip/hip_runtime.h>

#define IN_DIM  4096
#define OUT_DIM 4096
#define RANK    16
#define NBLK    16
#define KDIM    256   // NBLK*RANK

typedef __attribute__((ext_vector_type(8))) __bf16 bf16x8;
typedef __attribute__((ext_vector_type(4))) __bf16 bf16x4;
typedef __attribute__((ext_vector_type(4))) float  f32x4;

// ---------------------------------------------------------------------------
// Pack layouts (MFMA 16x16x32 fragment order), granularity = bf16x8 (16B):
//   PackA[mt(128)][ko(32)][c(16)] : 8 bf16 = T[mt*16+c][ko*8+j]   (A row=c)
//   PackB[nt(256)][ko(32)][c(16)] : 8 bf16 = Ahat[ko*8+j][nt*16+c](B col=c)
//   PackV[i(16)][ks(8)][qt(4)][c(16)] : 8 bf16 = Vt[i][ks*32+qt*8+j][c]
// apply GEMM: out = [Ahi|Alo] (m x 2K) @ [Bhi;Bhi] (2K x n)  (K'=512 concat;
// T kept to ~16-bit mantissa, weights single-bf16; A*Blo term dropped).
// ---------------------------------------------------------------------------

__device__ __forceinline__ void split_bf16(float v, __bf16& h, __bf16& l) {
    h = (__bf16)v;
    l = (__bf16)(v - (float)h);
}

// blocks 0..511: B-pack (Ahat = S*U, bf16-hi only).  blocks 512..543: Vt-pack.
__global__ __launch_bounds__(256) void build_packs(const float* __restrict__ S,
                                                   const float* __restrict__ U,
                                                   const float* __restrict__ Vt,
                                                   bf16x8* __restrict__ Bhi,
                                                   bf16x8* __restrict__ Vhi,
                                                   bf16x8* __restrict__ Vlo) {
    const int blk = blockIdx.x;
    if (blk < 512) {
        int t  = blk * 256 + threadIdx.x;  // = (nt*32 + ko)*16 + c
        int c  = t & 15;
        int ko = (t >> 4) & 31;
        int nt = t >> 9;
        int o  = nt >> 4;
        int i  = ko >> 1;
        int q  = ((nt & 15) << 4) | c;
        int r0 = (ko & 1) << 3;
        const float* Sp = S + ((o * NBLK + i) * RANK + r0);
        const float* Up = U + (size_t)o * RANK * 256 + q;   // + r*256
        bf16x8 hi;
#pragma unroll
        for (int j = 0; j < 8; ++j) {
            float w = Sp[j] * Up[(size_t)(r0 + j) * 256];
            hi[j] = (__bf16)w;
        }
        Bhi[t] = hi;
    } else {
        int t  = (blk - 512) * 256 + threadIdx.x;  // = ((i*8+ks)*4+qt)*16 + c
        int c  = t & 15;
        int p0 = (t >> 4) << 3;                    // (ks*32 + qt*8) within block i
        int i  = t >> 9;
        int pbase = (p0 & 255);
        const float* vp = Vt + ((size_t)(i * 256 + pbase)) * RANK + c;
        bf16x8 hi, lo;
#pragma unroll
        for (int j = 0; j < 8; ++j) {
            float w = vp[(size_t)j * RANK];
            __bf16 h, l;
            split_bf16(w, h, l);
            hi[j] = h; lo[j] = l;
        }
        Vhi[t] = hi;
        Vlo[t] = lo;
    }
}

// Stage A via MFMA:  D[r][m] = sum_p Vt[i][p][r] * x[m][p]  (per (mt, i) job)
__global__ __launch_bounds__(256) void factor_mfma(const float* __restrict__ x,
                                                   const bf16x8* __restrict__ Vhi,
                                                   const bf16x8* __restrict__ Vlo,
                                                   bf16x4* __restrict__ Ahi4,
                                                   bf16x4* __restrict__ Alo4,
                                                   float* __restrict__ rowsum_p,
                                                   int M) {
    const int tid = threadIdx.x;
    const int l   = tid & 63;
    const int w   = tid >> 6;
    const int job = blockIdx.x * 4 + w;     // (mt, i)
    const int i   = job & 15;
    const int mt  = job >> 4;
    const int row = l & 15;                 // m within tile (B col)
    const int qt  = l >> 4;                 // k-quarter

    const float* xp = x + (size_t)(mt * 16 + row) * IN_DIM + i * 256 + qt * 8;

    f32x4 acc = {0.f, 0.f, 0.f, 0.f};
    float rs = 0.f;
#pragma unroll
    for (int ks = 0; ks < 8; ++ks) {
        float4 a = *reinterpret_cast<const float4*>(xp + ks * 32);
        float4 b = *reinterpret_cast<const float4*>(xp + ks * 32 + 4);
        rs += (a.x + a.y) + (a.z + a.w) + (b.x + b.y) + (b.z + b.w);
        float vv[8] = {a.x, a.y, a.z, a.w, b.x, b.y, b.z, b.w};
        bf16x8 xh, xl;
#pragma unroll
        for (int jj = 0; jj < 8; ++jj) {
            __bf16 h, lo_;
            split_bf16(vv[jj], h, lo_);
            xh[jj] = h; xl[jj] = lo_;
        }
        size_t vidx = (size_t)((i * 8 + ks) * 4 + qt) * 16 + row;
        bf16x8 vh = Vhi[vidx];
        bf16x8 vl = Vlo[vidx];
        acc = __builtin_amdgcn_mfma_f32_16x16x32_bf16(vh, xh, acc, 0, 0, 0);
        acc = __builtin_amdgcn_mfma_f32_16x16x32_bf16(vh, xl, acc, 0, 0, 0);
        acc = __builtin_amdgcn_mfma_f32_16x16x32_bf16(vl, xh, acc, 0, 0, 0);
    }

    rs += __shfl_xor(rs, 16, 64);
    rs += __shfl_xor(rs, 32, 64);
    if (l < 16)
        rowsum_p[(size_t)i * M + mt * 16 + l] = rs;

    bf16x4 hi, lo;
#pragma unroll
    for (int reg = 0; reg < 4; ++reg) {
        __bf16 h, lo_;
        split_bf16(acc[reg], h, lo_);
        hi[reg] = h; lo[reg] = lo_;
    }
    size_t o4 = ((size_t)(mt * 32 + i * 2 + (l >> 5)) * 16 + row) * 2 + ((l >> 4) & 1);
    Ahi4[o4] = hi;
    Alo4[o4] = lo;
}

// out = [Ah|Al] @ [Bh;Bh] + (1+rowsum[m])*bias[n].
// Tile 128m x 128n, 512 blocks (1 full co-residency pass at 3 blk/CU),
// 4 waves (2x2, each 64m x 64n), K=256 in 8 steps of 32.
// LDS/step: A-hi 8KB + A-lo 8KB + B-hi 8KB = 24KB; dbuf 48KB.
__global__ __launch_bounds__(256, 3) void apply_mfma(const bf16x8* __restrict__ Ahi,
                                                     const bf16x8* __restrict__ Alo,
                                                     const bf16x8* __restrict__ Bhi,
                                                     const float* __restrict__ rowsum_p,
                                                     const float* __restrict__ bias,
                                                     float* __restrict__ out, int M) {
    __shared__ bf16x8 smem[2][1536];   // [buf][sl(24)*64]: 0-7 A-hi, 8-15 A-lo, 16-23 B-hi
    __shared__ float rstot_s[128];

    const int nb  = blockIdx.x;
    const int q   = gridDim.x >> 3;             // 64 (grid 512, %8==0)
    const int lg  = (nb & 7) * q + (nb >> 3);   // XCD-contiguous logical id
    const int mr  = lg & 15;
    const int nc  = lg >> 4;                    // 4 consecutive nc per XCD
    const int m0  = mr * 128, n0 = nc * 128;
    const int mtb0 = m0 >> 4;                   // 8 mt-tiles
    const int ntb0 = n0 >> 4;                   // 8 nt-tiles

    const int tid = threadIdx.x;
    const int l   = tid & 63;
    const int w   = __builtin_amdgcn_readfirstlane(tid >> 6);
    const int wm  = w & 1, wn = w >> 1;         // 2x2 waves: 64m x 64n each
    const int kq  = l >> 4, c = l & 15;

    // stage one 24KB K-step chunk into buffer buf_; 6 slices (1KB each) per wave
#define STAGE(s_, buf_)                                                              \
    {                                                                                \
        _Pragma("unroll")                                                            \
        for (int j = 0; j < 6; ++j) {                                                \
            const int sl = w * 6 + j;                                                \
            const bf16x8* gbase;                                                     \
            if (sl < 8)                                                              \
                gbase = Ahi + ((size_t)((mtb0 + sl) * 32 + 4 * (s_)) * 16);          \
            else if (sl < 16)                                                        \
                gbase = Alo + ((size_t)((mtb0 + sl - 8) * 32 + 4 * (s_)) * 16);      \
            else                                                                     \
                gbase = Bhi + ((size_t)((ntb0 + sl - 16) * 32 + 4 * (s_)) * 16);     \
            __builtin_amdgcn_global_load_lds(                                        \
                (const __attribute__((address_space(1))) unsigned*)(gbase + l),      \
                (__attribute__((address_space(3))) unsigned*)&smem[buf_][sl * 64],   \
                16, 0, 0);                                                           \
        }                                                                            \
    }

    f32x4 acc[4][4];
#pragma unroll
    for (int f = 0; f < 4; ++f)
#pragma unroll
        for (int nf = 0; nf < 4; ++nf) acc[f][nf] = f32x4{0.f, 0.f, 0.f, 0.f};

    STAGE(0, 0);
    if (tid < 128) {
        float ssum = 1.0f;
#pragma unroll
        for (int i = 0; i < NBLK; ++i) ssum += rowsum_p[(size_t)i * M + m0 + tid];
        rstot_s[tid] = ssum;
    }
    __syncthreads();

    for (int s = 0; s < 8; ++s) {
        if (s < 7) STAGE(s + 1, (s + 1) & 1);
        const bf16x8* sb = smem[s & 1];
        bf16x8 ah[4], al[4];
#pragma unroll
        for (int f = 0; f < 4; ++f) {
            ah[f] = sb[(wm * 4 + f) * 64 + l];
            al[f] = sb[512 + (wm * 4 + f) * 64 + l];
        }
#pragma unroll
        for (int nf = 0; nf < 4; ++nf) {
            bf16x8 bh = sb[1024 + (wn * 4 + nf) * 64 + l];
#pragma unroll
            for (int f = 0; f < 4; ++f) {
                acc[f][nf] = __builtin_amdgcn_mfma_f32_16x16x32_bf16(ah[f], bh, acc[f][nf], 0, 0, 0);
                acc[f][nf] = __builtin_amdgcn_mfma_f32_16x16x32_bf16(al[f], bh, acc[f][nf], 0, 0, 0);
            }
        }
        __syncthreads();
    }
#undef STAGE

    // epilogue: out[m][n] = acc + rstot[m]*bias[n]   (C/D: row=kq*4+reg, col=c)
#pragma unroll
    for (int f = 0; f < 4; ++f) {
        const int rloc = wm * 64 + f * 16 + kq * 4;
        const int rowb = m0 + rloc;
        float rsv[4];
#pragma unroll
        for (int reg = 0; reg < 4; ++reg) rsv[reg] = rstot_s[rloc + reg];
#pragma unroll
        for (int nf = 0; nf < 4; ++nf) {
            const int n = n0 + wn * 64 + nf * 16 + c;
            const float bv = bias[n];
#pragma unroll
            for (int reg = 0; reg < 4; ++reg)
                out[(size_t)(rowb + reg) * OUT_DIM + n] = acc[f][nf][reg] + rsv[reg] * bv;
        }
    }
}

extern "C" void kernel_launch(void* const* d_in, const int* in_sizes, int n_in,
                              void* d_out, int out_size, void* d_ws, size_t ws_size,
                              hipStream_t stream) {
    const float* x    = (const float*)d_in[0];
    const float* S    = (const float*)d_in[1];
    const float* U    = (const float*)d_in[2];
    const float* Vt   = (const float*)d_in[3];
    const float* bias = (const float*)d_in[4];
    float* out = (float*)d_out;
    const int M = in_sizes[0] / IN_DIM;   // 2048

    char* ws = (char*)d_ws;
    bf16x8* Bhi     = (bf16x8*)ws;                                    // 2 MB
    bf16x8* Ahi     = (bf16x8*)(ws + (2u << 20));                     // 1 MB
    bf16x8* Alo     = (bf16x8*)(ws + (3u << 20));                     // 1 MB
    bf16x8* Vhi     = (bf16x8*)(ws + (4u << 20));                     // 128 KB
    bf16x8* Vlo     = (bf16x8*)(ws + (4u << 20) + (128u << 10));      // 128 KB
    float* rowsum_p = (float*)(ws + (4u << 20) + (256u << 10));       // 128 KB

    build_packs<<<544, 256, 0, stream>>>(S, U, Vt, Bhi, Vhi, Vlo);
    factor_mfma<<<M / 4, 256, 0, stream>>>(x, Vhi, Vlo,
                                           (bf16x4*)Ahi, (bf16x4*)Alo, rowsum_p, M);
    apply_mfma<<<(M / 128) * (OUT_DIM / 128), 256, 0, stream>>>(
        Ahi, Alo, Bhi, rowsum_p, bias, out, M);
}